// Round 4
// baseline (9208.562 us; speedup 1.0000x reference)
//
#include <hip/hip_runtime.h>

// Problem constants (fixed by the reference).
#define NSTEP 16384   // scan length (== B)
#define NCH   20      // independent chains (== T)
// hidden = 32, gates = 128 per layer (torch order i,f,g,o).

// Raw barrier: order LDS (lgkmcnt) but leave global loads/stores in flight.
#define BAR() asm volatile("s_waitcnt lgkmcnt(0)\n\ts_barrier" ::: "memory")

__device__ __forceinline__ float rl(float v, int l) {
  return __builtin_bit_cast(float, __builtin_amdgcn_readlane(__builtin_bit_cast(int, v), l));
}
__device__ __forceinline__ float sigm(float x) { return 1.0f / (1.0f + __expf(-x)); }
__device__ __forceinline__ float tanh_(float x) {
  return 1.0f - 2.0f / (1.0f + __expf(2.0f * x));   // inf-safe
}

// In-loop register pin: asserts these values live in VGPRs and may be
// modified here -> the allocator can neither spill-reload nor rematerialize
// (re-load from L1) them across iterations. Zero instructions emitted.
#define PINW8(a, o) asm volatile("" : "+v"(a[o]), "+v"(a[o+1]), "+v"(a[o+2]), \
  "+v"(a[o+3]), "+v"(a[o+4]), "+v"(a[o+5]), "+v"(a[o+6]), "+v"(a[o+7]))

// 6 waves (384 threads), one block per chain n.
// Every wave keeps exactly 32 weights in ONE unified w[32] array (single
// live range shared by all role branches), pinned in-loop (see PINW8).
//
// Roles / software pipeline (iteration it, one barrier per iteration):
//  waves 0,1: layer-1. Update c1,h1 from gates(it-1), then compute
//             gates(it) = sigma/tanh(b + x(it)@Wih1^T + h1@Whh1^T) -> g1buf.
//  waves 4,5: pin(tp=it-2) = h1(tp)@Wih2^T + b2 -> pinbuf; also stage x.
//  waves 2,3: layer-2. Update c2,h2 from gates2(it-4) (store ys2), then
//             gates2(tg=it-3) from pinbuf(tg) + h2@Whh2^T -> g2buf.
__global__ __launch_bounds__(384, 1)
void lstm2_kernel(const float* __restrict__ x,
                  const float* __restrict__ Wih1, const float* __restrict__ Whh1,
                  const float* __restrict__ bih1, const float* __restrict__ bhh1,
                  const float* __restrict__ Wih2, const float* __restrict__ Whh2,
                  const float* __restrict__ bih2, const float* __restrict__ bhh2,
                  float* __restrict__ ys2)
{
  const int n    = blockIdx.x;
  const int tid  = threadIdx.x;
  const int wave = tid >> 6;
  const int lane = tid & 63;
  const int u    = lane & 31;

  __shared__ __align__(16) float g1buf[2][128];    // [u*4 + gate] i,f,g~,o
  __shared__ __align__(16) float g2buf[2][128];
  __shared__ __align__(16) float h1buf[2][32];
  __shared__ __align__(16) float pinbuf[2][128];
  __shared__ __align__(16) float xbuf[2][64 * 6];  // x in 64-step chunks

  // ---- unified role setup: ONE weight array, ONE bias ----
  const int L    = (wave >= 4) ? (wave - 4) * 64 + lane : 0;  // proj row
  const int tloc = L >> 1;
  const int i0   = (L & 1) * 3;

  const float* wsrc;
  float bv = 0.f;
  if (wave < 2) {
    const int row = wave * 64 + lane;
    wsrc = Whh1 + row * 32;
    bv = bih1[row] + bhh1[row];
  } else if (wave < 4) {
    const int row = (wave - 2) * 64 + lane;
    wsrc = Whh2 + row * 32;
  } else {
    wsrc = Wih2 + L * 32;
    bv = bih2[L] + bhh2[L];
  }
  float w[32];
#pragma unroll
  for (int k = 0; k < 32; ++k) w[k] = wsrc[k];

  float wI[6] = {0.f, 0.f, 0.f, 0.f, 0.f, 0.f};
  if (wave < 2) {
    const int row = wave * 64 + lane;
#pragma unroll
    for (int k = 0; k < 6; ++k) wI[k] = Wih1[row * 6 + k];
  } else if (wave >= 4) {
    // prologue: stage x chunk 0
    const float* xp = x + ((size_t)tloc * NCH + n) * 6 + i0;
    const float a0 = xp[0], a1 = xp[1], a2 = xp[2];
    float* xd = &xbuf[0][L * 3];
    xd[0] = a0; xd[1] = a1; xd[2] = a2;
  }

  float hval = 0.f, cval = 0.f;
  float sx0 = 0.f, sx1 = 0.f, sx2 = 0.f;

  for (int it = 0; it < NSTEP + 4; ++it) {
    BAR();   // single barrier per step; vmcnt never drained in-loop

    // Force all weights register-resident at every iteration.
    PINW8(w, 0); PINW8(w, 8); PINW8(w, 16); PINW8(w, 24);
    asm volatile("" : "+v"(wI[0]), "+v"(wI[1]), "+v"(wI[2]),
                      "+v"(wI[3]), "+v"(wI[4]), "+v"(wI[5]), "+v"(bv));

    if (wave < 2) {
      // ---- layer 1 ----
      if (it >= 1 && it <= NSTEP) {          // update c1,h1 from gates(it-1)
        const float4 gv = *(const float4*)&g1buf[(it - 1) & 1][u * 4];
        cval = fmaf(gv.y, cval, gv.x * gv.z);
        hval = gv.w * tanh_(cval);
        if (wave == 0 && lane < 32) h1buf[(it - 1) & 1][u] = hval;
      }
      if (it < NSTEP) {                      // gates(it) using fresh h1
        const float* xb = &xbuf[(it >> 6) & 1][(it & 63) * 6];
        const float2 xa = *(const float2*)(xb + 0);
        const float2 xm = *(const float2*)(xb + 2);
        const float2 xc = *(const float2*)(xb + 4);
        float xacc = bv;
        xacc = fmaf(xa.x, wI[0], xacc); xacc = fmaf(xa.y, wI[1], xacc);
        xacc = fmaf(xm.x, wI[2], xacc); xacc = fmaf(xm.y, wI[3], xacc);
        xacc = fmaf(xc.x, wI[4], xacc); xacc = fmaf(xc.y, wI[5], xacc);
        float acc0 = 0.f, acc1 = 0.f;
#pragma unroll
        for (int k = 0; k < 32; k += 2) {
          acc0 = fmaf(rl(hval, k),     w[k],     acc0);
          acc1 = fmaf(rl(hval, k + 1), w[k + 1], acc1);
        }
        const float acc = xacc + acc0 + acc1;
        const bool istanh = (wave == 1) && (lane < 32);   // g-gate rows 64..95
        const float v = istanh ? tanh_(acc) : sigm(acc);
        g1buf[it & 1][u * 4 + (wave * 2 + (lane >> 5))] = v;
      }
    } else if (wave < 4) {
      // ---- layer 2 ----
      if (it >= 4 && it <= NSTEP + 3) {      // update c2,h2 from gates2(it-4)
        const float4 gv = *(const float4*)&g2buf[(it - 4) & 1][u * 4];
        cval = fmaf(gv.y, cval, gv.x * gv.z);
        hval = gv.w * tanh_(cval);
        if (wave == 2 && lane < 32)
          ys2[((size_t)(it - 4) * NCH + n) * 32 + u] = hval;
      }
      if (it >= 3 && it <= NSTEP + 2) {      // gates2(tg) using fresh h2
        const int tg = it - 3;
        const float pinv = pinbuf[tg & 1][(wave - 2) * 64 + lane];
        float acc0 = 0.f, acc1 = 0.f;
#pragma unroll
        for (int k = 0; k < 32; k += 2) {
          acc0 = fmaf(rl(hval, k),     w[k],     acc0);
          acc1 = fmaf(rl(hval, k + 1), w[k + 1], acc1);
        }
        const float acc = pinv + acc0 + acc1;
        const bool istanh = (wave == 3) && (lane < 32);   // g-gate rows
        const float v = istanh ? tanh_(acc) : sigm(acc);
        g2buf[tg & 1][u * 4 + ((wave - 2) * 2 + (lane >> 5))] = v;
      }
    } else {
      // ---- projection + x staging ----
      if ((it & 63) == 0) {                  // issue next-chunk loads
        const int cn = (it >> 6) + 1;
        if (cn < NSTEP / 64) {
          const float* xp = x + ((size_t)(cn * 64 + tloc) * NCH + n) * 6 + i0;
          sx0 = xp[0]; sx1 = xp[1]; sx2 = xp[2];
        }
      } else if ((it & 63) == 16) {          // write 16 iters later (latency hidden)
        const int cn = (it >> 6) + 1;
        if (cn < NSTEP / 64) {
          float* xd = &xbuf[cn & 1][L * 3];
          xd[0] = sx0; xd[1] = sx1; xd[2] = sx2;
        }
      }
      if (it >= 2 && it <= NSTEP + 1) {      // pin(tp) = h1(tp)@Wih2^T + b2
        const int tp = it - 2;
        const float4* hb = (const float4*)h1buf[tp & 1];  // broadcast reads
        float a0 = bv, a1 = 0.f;
#pragma unroll
        for (int q = 0; q < 8; q += 2) {
          const float4 h0 = hb[q], h1v = hb[q + 1];
          a0 = fmaf(h0.x,  w[4*q + 0], a0); a1 = fmaf(h0.y,  w[4*q + 1], a1);
          a0 = fmaf(h0.z,  w[4*q + 2], a0); a1 = fmaf(h0.w,  w[4*q + 3], a1);
          a0 = fmaf(h1v.x, w[4*q + 4], a0); a1 = fmaf(h1v.y, w[4*q + 5], a1);
          a0 = fmaf(h1v.z, w[4*q + 6], a0); a1 = fmaf(h1v.w, w[4*q + 7], a1);
        }
        pinbuf[tp & 1][L] = a0 + a1;
      }
    }
  }
}

// MLP head: z(16384,640) -> relu(640->128) -> relu(128->32) -> 2.
__global__ __launch_bounds__(128, 1)
void head_kernel(const float* __restrict__ ys2,
                 const float* __restrict__ W1, const float* __restrict__ b1,
                 const float* __restrict__ W2, const float* __restrict__ b2,
                 const float* __restrict__ W3, const float* __restrict__ b3,
                 float* __restrict__ out)
{
  const int R = 16;
  const int b0 = blockIdx.x * R;
  const int tid = threadIdx.x;

  __shared__ __align__(16) float zl[R][640];
  __shared__ float z1[R][128];
  __shared__ float z2[R][32];

  {
    const float4* src = (const float4*)(ys2 + (size_t)b0 * 640);
    float4* dst = (float4*)&zl[0][0];
    for (int i = tid; i < R * 160; i += 128) dst[i] = src[i];
  }
  __syncthreads();

  {
    float acc[R];
    const float bb = b1[tid];
#pragma unroll
    for (int r = 0; r < R; ++r) acc[r] = bb;
    for (int kk = 0; kk < 640; kk += 4) {
      const float4 w = *(const float4*)&W1[(size_t)tid * 640 + kk];
#pragma unroll
      for (int r = 0; r < R; ++r) {
        const float4 z4 = *(const float4*)&zl[r][kk];
        acc[r] = fmaf(w.x, z4.x, fmaf(w.y, z4.y, fmaf(w.z, z4.z, fmaf(w.w, z4.w, acc[r]))));
      }
    }
#pragma unroll
    for (int r = 0; r < R; ++r) z1[r][tid] = fmaxf(acc[r], 0.f);
  }
  __syncthreads();

  {
    const int jo = tid & 31, rg = tid >> 5;
    float a2[4];
    const float bb = b2[jo];
#pragma unroll
    for (int q = 0; q < 4; ++q) a2[q] = bb;
    for (int k = 0; k < 128; ++k) {
      const float w = W2[jo * 128 + k];
#pragma unroll
      for (int q = 0; q < 4; ++q) a2[q] = fmaf(w, z1[rg + 4 * q][k], a2[q]);
    }
#pragma unroll
    for (int q = 0; q < 4; ++q) z2[rg + 4 * q][jo] = fmaxf(a2[q], 0.f);
  }
  __syncthreads();

  if (tid < 32) {
    const int r = tid >> 1, jo = tid & 1;
    float a = b3[jo];
#pragma unroll
    for (int k = 0; k < 32; ++k) a = fmaf(W3[jo * 32 + k], z2[r][k], a);
    out[(size_t)(b0 + r) * 2 + jo] = a;
  }
}

extern "C" void kernel_launch(void* const* d_in, const int* in_sizes, int n_in,
                              void* d_out, int out_size, void* d_ws, size_t ws_size,
                              hipStream_t stream) {
  (void)in_sizes; (void)n_in; (void)out_size; (void)ws_size;
  const float* x    = (const float*)d_in[0];
  const float* Wih1 = (const float*)d_in[1];
  const float* Whh1 = (const float*)d_in[2];
  const float* bih1 = (const float*)d_in[3];
  const float* bhh1 = (const float*)d_in[4];
  const float* Wih2 = (const float*)d_in[5];
  const float* Whh2 = (const float*)d_in[6];
  const float* bih2 = (const float*)d_in[7];
  const float* bhh2 = (const float*)d_in[8];
  const float* W1   = (const float*)d_in[9];
  const float* b1   = (const float*)d_in[10];
  const float* W2   = (const float*)d_in[11];
  const float* b2   = (const float*)d_in[12];
  const float* W3   = (const float*)d_in[13];
  const float* b3   = (const float*)d_in[14];
  float* out = (float*)d_out;

  float* ys2 = (float*)d_ws;   // (16384, 20, 32) fp32 = 41.9 MB

  lstm2_kernel<<<NCH, 384, 0, stream>>>(x, Wih1, Whh1, bih1, bhh1,
                                        Wih2, Whh2, bih2, bhh2, ys2);
  head_kernel<<<NSTEP / 16, 128, 0, stream>>>(ys2, W1, b1, W2, b2, W3, b3, out);
}

// Round 5
// 8053.725 us; speedup vs baseline: 1.1434x; 1.1434x over previous
//
#include <hip/hip_runtime.h>

// Problem constants (fixed by the reference).
#define NSTEP 16384   // scan length (== B)
#define NCH   20      // independent chains (== T)
#define D     16      // steps per barrier block
#define NB    (NSTEP / D)   // 1024 blocks
// hidden = 32, gates = 128 per layer (torch order i,f,g,o).

// Raw barrier: order LDS (lgkmcnt) but leave global loads/stores in flight.
#define BAR() asm volatile("s_waitcnt lgkmcnt(0)\n\ts_barrier" ::: "memory")

__device__ __forceinline__ float rl(float v, int l) {
  return __builtin_bit_cast(float, __builtin_amdgcn_readlane(__builtin_bit_cast(int, v), l));
}
__device__ __forceinline__ float sigm(float x) { return 1.0f / (1.0f + __expf(-x)); }
__device__ __forceinline__ float tanh_(float x) {
  return 1.0f - 2.0f / (1.0f + __expf(2.0f * x));   // inf-safe
}

// 4 waves (256 threads), one block per chain n, 1 wave/SIMD.
// Block-pipelined: ONE barrier per D=16 steps. Per-step recurrences are
// fully in-wave (readlane dot + shfl_xor gate exchange), no LDS round-trip.
//
// Pipeline (block index b, one barrier between consecutive b):
//   wave0 (L1):   steps [bD,(b+1)D): h1 recurrence; needs pin1[b] (made at b-1);
//                 writes h1 -> h1s[b&1].
//   waves2,3:     pin1 for block b+1 (from x, direct global uniform loads);
//                 pin2 for block b-1 (from h1s[(b-1)&1]).
//   wave1 (L2):   steps of block b-2: h2 recurrence; needs pin2[b-2] (made at b-1);
//                 stores ys2.
__global__ __launch_bounds__(256, 1)
void lstm2_kernel(const float* __restrict__ x,
                  const float* __restrict__ Wih1, const float* __restrict__ Whh1,
                  const float* __restrict__ bih1, const float* __restrict__ bhh1,
                  const float* __restrict__ Wih2, const float* __restrict__ Whh2,
                  const float* __restrict__ bih2, const float* __restrict__ bhh2,
                  float* __restrict__ ys2)
{
  const int n    = blockIdx.x;
  const int tid  = threadIdx.x;
  const int wave = tid >> 6;
  const int lane = tid & 63;
  const int u    = lane & 31;
  const bool lower = (lane < 32);

  __shared__ __align__(16) float h1s [2][D][32];
  __shared__ __align__(16) float pin1[2][D][128];
  __shared__ __align__(16) float pin2[2][D][128];

  const int r = (wave >= 2) ? (wave - 2) * 64 + lane : 0;   // helper proj row

  // Per-role weights. w0/w1: recurrent rows (lane, lane+64) for L1/L2 waves;
  // w0: Wih2 row r for helpers. Single arrays shared across roles.
  float w0[32] = {}, w1[32] = {};
  float wI[6] = {};
  float bp1 = 0.f, bp2 = 0.f;

  if (wave == 0) {
#pragma unroll
    for (int k = 0; k < 32; ++k) {
      w0[k] = Whh1[lane * 32 + k];
      w1[k] = Whh1[(lane + 64) * 32 + k];
    }
  } else if (wave == 1) {
#pragma unroll
    for (int k = 0; k < 32; ++k) {
      w0[k] = Whh2[lane * 32 + k];
      w1[k] = Whh2[(lane + 64) * 32 + k];
    }
  } else {
#pragma unroll
    for (int k = 0; k < 32; ++k) w0[k] = Wih2[r * 32 + k];
#pragma unroll
    for (int k = 0; k < 6; ++k)  wI[k] = Wih1[r * 6 + k];
    bp1 = bih1[r] + bhh1[r];
    bp2 = bih2[r] + bhh2[r];
  }

  float hval = 0.f, cval = 0.f;

  // ---- pre-loop: helpers compute pin1 for block 0 (x read direct) ----
  if (wave >= 2) {
#pragma unroll
    for (int j = 0; j < D; ++j) {
      const float* xp = x + ((size_t)j * NCH + n) * 6;
      const float2 xa = *(const float2*)(xp + 0);
      const float2 xm = *(const float2*)(xp + 2);
      const float2 xc = *(const float2*)(xp + 4);
      float acc = bp1;
      acc = fmaf(xa.x, wI[0], acc); acc = fmaf(xa.y, wI[1], acc);
      acc = fmaf(xm.x, wI[2], acc); acc = fmaf(xm.y, wI[3], acc);
      acc = fmaf(xc.x, wI[4], acc); acc = fmaf(xc.y, wI[5], acc);
      pin1[0][j][r] = acc;
    }
  }

  for (int b = 0; b < NB + 2; ++b) {
    BAR();   // one barrier per D steps; vmcnt never drained in-loop
    const int p = b & 1;

    if (wave == 0) {
      // ---- layer-1: D steps fully in-wave ----
      if (b < NB) {
        float pa[D], pb[D];
#pragma unroll
        for (int j = 0; j < D; ++j) {
          pa[j] = pin1[p][j][lane];
          pb[j] = pin1[p][j][lane + 64];
        }
#pragma unroll
        for (int j = 0; j < D; ++j) {
          float acc0 = pa[j], acc1 = pb[j];
#pragma unroll
          for (int k = 0; k < 32; ++k) {
            const float hk = rl(hval, k);
            acc0 = fmaf(hk, w0[k], acc0);
            acc1 = fmaf(hk, w1[k], acc1);
          }
          // lower lane: rows (i,g); upper lane: rows (f,o) for unit u
          float Aval, Bval;
          if (lower) { Aval = sigm(acc0) * tanh_(acc1); Bval = 0.f; }
          else       { Aval = sigm(acc0); Bval = sigm(acc1); }
          const float rA = __shfl_xor(Aval, 32, 64);
          const float rB = __shfl_xor(Bval, 32, 64);
          const float fv = lower ? rA : Aval;
          const float ig = lower ? Aval : rA;
          const float ov = lower ? rB : Bval;
          cval = fmaf(fv, cval, ig);
          hval = ov * tanh_(cval);
          if (lower) h1s[p][j][u] = hval;
        }
      }
    } else if (wave == 1) {
      // ---- layer-2: D steps of block b-2 ----
      if (b >= 2) {
        const int t0 = (b - 2) * D;
        float pa[D], pb[D];
#pragma unroll
        for (int j = 0; j < D; ++j) {
          pa[j] = pin2[p][j][lane];
          pb[j] = pin2[p][j][lane + 64];
        }
#pragma unroll
        for (int j = 0; j < D; ++j) {
          float acc0 = pa[j], acc1 = pb[j];
#pragma unroll
          for (int k = 0; k < 32; ++k) {
            const float hk = rl(hval, k);
            acc0 = fmaf(hk, w0[k], acc0);
            acc1 = fmaf(hk, w1[k], acc1);
          }
          float Aval, Bval;
          if (lower) { Aval = sigm(acc0) * tanh_(acc1); Bval = 0.f; }
          else       { Aval = sigm(acc0); Bval = sigm(acc1); }
          const float rA = __shfl_xor(Aval, 32, 64);
          const float rB = __shfl_xor(Bval, 32, 64);
          const float fv = lower ? rA : Aval;
          const float ig = lower ? Aval : rA;
          const float ov = lower ? rB : Bval;
          cval = fmaf(fv, cval, ig);
          hval = ov * tanh_(cval);
          if (lower) ys2[((size_t)(t0 + j) * NCH + n) * 32 + u] = hval;
        }
      }
    } else {
      // ---- helpers: pin2 for block b-1, pin1 for block b+1 ----
      if (b >= 1 && b <= NB) {
        const int q = (b - 1) & 1;
#pragma unroll
        for (int j = 0; j < D; ++j) {
          const float4* hb = (const float4*)&h1s[q][j][0];   // broadcast reads
          float a0 = bp2, a1 = 0.f;
#pragma unroll
          for (int qq = 0; qq < 8; qq += 2) {
            const float4 h0 = hb[qq], h1v = hb[qq + 1];
            a0 = fmaf(h0.x,  w0[4*qq + 0], a0); a1 = fmaf(h0.y,  w0[4*qq + 1], a1);
            a0 = fmaf(h0.z,  w0[4*qq + 2], a0); a1 = fmaf(h0.w,  w0[4*qq + 3], a1);
            a0 = fmaf(h1v.x, w0[4*qq + 4], a0); a1 = fmaf(h1v.y, w0[4*qq + 5], a1);
            a0 = fmaf(h1v.z, w0[4*qq + 6], a0); a1 = fmaf(h1v.w, w0[4*qq + 7], a1);
          }
          pin2[q][j][r] = a0 + a1;
        }
      }
      if (b + 1 < NB) {
        const int s = (b + 1) & 1;
        const int tb = (b + 1) * D;
#pragma unroll
        for (int j = 0; j < D; ++j) {
          const float* xp = x + ((size_t)(tb + j) * NCH + n) * 6;  // uniform addr
          const float2 xa = *(const float2*)(xp + 0);
          const float2 xm = *(const float2*)(xp + 2);
          const float2 xc = *(const float2*)(xp + 4);
          float acc = bp1;
          acc = fmaf(xa.x, wI[0], acc); acc = fmaf(xa.y, wI[1], acc);
          acc = fmaf(xm.x, wI[2], acc); acc = fmaf(xm.y, wI[3], acc);
          acc = fmaf(xc.x, wI[4], acc); acc = fmaf(xc.y, wI[5], acc);
          pin1[s][j][r] = acc;
        }
      }
    }
  }
}

// MLP head: z(16384,640) -> relu(640->128) -> relu(128->32) -> 2.
__global__ __launch_bounds__(128, 1)
void head_kernel(const float* __restrict__ ys2,
                 const float* __restrict__ W1, const float* __restrict__ b1,
                 const float* __restrict__ W2, const float* __restrict__ b2,
                 const float* __restrict__ W3, const float* __restrict__ b3,
                 float* __restrict__ out)
{
  const int R = 16;
  const int b0 = blockIdx.x * R;
  const int tid = threadIdx.x;

  __shared__ __align__(16) float zl[R][640];
  __shared__ float z1[R][128];
  __shared__ float z2[R][32];

  {
    const float4* src = (const float4*)(ys2 + (size_t)b0 * 640);
    float4* dst = (float4*)&zl[0][0];
    for (int i = tid; i < R * 160; i += 128) dst[i] = src[i];
  }
  __syncthreads();

  {
    float acc[R];
    const float bb = b1[tid];
#pragma unroll
    for (int r = 0; r < R; ++r) acc[r] = bb;
    for (int kk = 0; kk < 640; kk += 4) {
      const float4 w = *(const float4*)&W1[(size_t)tid * 640 + kk];
#pragma unroll
      for (int r = 0; r < R; ++r) {
        const float4 z4 = *(const float4*)&zl[r][kk];
        acc[r] = fmaf(w.x, z4.x, fmaf(w.y, z4.y, fmaf(w.z, z4.z, fmaf(w.w, z4.w, acc[r]))));
      }
    }
#pragma unroll
    for (int r = 0; r < R; ++r) z1[r][tid] = fmaxf(acc[r], 0.f);
  }
  __syncthreads();

  {
    const int jo = tid & 31, rg = tid >> 5;
    float a2[4];
    const float bb = b2[jo];
#pragma unroll
    for (int q = 0; q < 4; ++q) a2[q] = bb;
    for (int k = 0; k < 128; ++k) {
      const float w = W2[jo * 128 + k];
#pragma unroll
      for (int q = 0; q < 4; ++q) a2[q] = fmaf(w, z1[rg + 4 * q][k], a2[q]);
    }
#pragma unroll
    for (int q = 0; q < 4; ++q) z2[rg + 4 * q][jo] = fmaxf(a2[q], 0.f);
  }
  __syncthreads();

  if (tid < 32) {
    const int r = tid >> 1, jo = tid & 1;
    float a = b3[jo];
#pragma unroll
    for (int k = 0; k < 32; ++k) a = fmaf(W3[jo * 32 + k], z2[r][k], a);
    out[(size_t)(b0 + r) * 2 + jo] = a;
  }
}

extern "C" void kernel_launch(void* const* d_in, const int* in_sizes, int n_in,
                              void* d_out, int out_size, void* d_ws, size_t ws_size,
                              hipStream_t stream) {
  (void)in_sizes; (void)n_in; (void)out_size; (void)ws_size;
  const float* x    = (const float*)d_in[0];
  const float* Wih1 = (const float*)d_in[1];
  const float* Whh1 = (const float*)d_in[2];
  const float* bih1 = (const float*)d_in[3];
  const float* bhh1 = (const float*)d_in[4];
  const float* Wih2 = (const float*)d_in[5];
  const float* Whh2 = (const float*)d_in[6];
  const float* bih2 = (const float*)d_in[7];
  const float* bhh2 = (const float*)d_in[8];
  const float* W1   = (const float*)d_in[9];
  const float* b1   = (const float*)d_in[10];
  const float* W2   = (const float*)d_in[11];
  const float* b2   = (const float*)d_in[12];
  const float* W3   = (const float*)d_in[13];
  const float* b3   = (const float*)d_in[14];
  float* out = (float*)d_out;

  float* ys2 = (float*)d_ws;   // (16384, 20, 32) fp32 = 41.9 MB

  lstm2_kernel<<<NCH, 256, 0, stream>>>(x, Wih1, Whh1, bih1, bhh1,
                                        Wih2, Whh2, bih2, bhh2, ys2);
  head_kernel<<<NSTEP / 16, 128, 0, stream>>>(ys2, W1, b1, W2, b2, W3, b3, out);
}

// Round 6
// 4806.007 us; speedup vs baseline: 1.9161x; 1.6758x over previous
//
#include <hip/hip_runtime.h>

// Problem constants (fixed by the reference).
#define NSTEP 16384   // scan length (== B)
#define NCH   20      // independent chains (== T)
#define D     16      // steps per barrier block
#define NB    (NSTEP / D)   // 1024 blocks
// hidden = 32, gates = 128 per layer (torch order i,f,g,o).

// Raw barrier: order LDS (lgkmcnt) but leave global loads/stores in flight.
#define BAR() asm volatile("s_waitcnt lgkmcnt(0)\n\ts_barrier" ::: "memory")

__device__ __forceinline__ float rl(float v, int l) {
  return __builtin_bit_cast(float, __builtin_amdgcn_readlane(__builtin_bit_cast(int, v), l));
}
// Raw transcendentals: v_exp_f32 (2^x) and v_rcp_f32 (~1ulp). Avoids the
// IEEE div sequence (v_div_scale/fmas/fixup, ~15 inst) that 1.0f/x emits
// without fast-math — that sequence was ~250cy/step across rounds 1-5.
__device__ __forceinline__ float vexp2(float x) {
  float r; asm("v_exp_f32 %0, %1" : "=v"(r) : "v"(x)); return r;
}
__device__ __forceinline__ float vrcp(float x) {
  float r; asm("v_rcp_f32 %0, %1" : "=v"(r) : "v"(x)); return r;
}
#define KNEG (-1.4426950408889634f)   // -log2(e)

__device__ __forceinline__ float tanhv(float x) {
  // tanh(x) = 2*sigma(2x)-1 ; inf-safe (exp2->inf => rcp->0 => -1).
  const float e = vexp2(x * (2.0f * KNEG));
  return fmaf(2.0f, vrcp(1.0f + e), -1.0f);
}

// 4 waves (256 threads), one block per chain n, 1 wave/SIMD.
// Block-pipelined: ONE barrier per D=16 steps. Per-step recurrences fully
// in-wave (readlane dot + shfl_xor gate exchange), branch-free activations.
// amdgpu_waves_per_eu(1,1): sets the scheduler's occupancy target to 1
// wave/EU so it stops sinking LDS/weight loads into the step loop to save
// registers (rounds 3-5 allocated only 40-64 VGPRs and re-read pins per
// step on the critical path).
//
// Pipeline (block index b, one barrier between consecutive b):
//   wave0 (L1): steps [bD,(b+1)D): h1 recurrence from pin1[b]; h1 -> h1s[b&1]
//   waves2,3:   pin2 for block b-1 (from h1s); pin1 for block b+1 (from
//               xstage LDS, staged one block ahead); stage x for b+2.
//   wave1 (L2): steps of block b-2 from pin2; stores ys2.
__global__ __attribute__((amdgpu_flat_work_group_size(256, 256),
                          amdgpu_waves_per_eu(1, 1)))
void lstm2_kernel(const float* __restrict__ x,
                  const float* __restrict__ Wih1, const float* __restrict__ Whh1,
                  const float* __restrict__ bih1, const float* __restrict__ bhh1,
                  const float* __restrict__ Wih2, const float* __restrict__ Whh2,
                  const float* __restrict__ bih2, const float* __restrict__ bhh2,
                  float* __restrict__ ys2)
{
  const int n    = blockIdx.x;
  const int tid  = threadIdx.x;
  const int wave = tid >> 6;
  const int lane = tid & 63;
  const int u    = lane & 31;
  const bool lower = (lane < 32);

  __shared__ __align__(16) float h1s [2][D][32];
  __shared__ __align__(16) float pin1[2][D][128];
  __shared__ __align__(16) float pin2[2][D][128];
  __shared__ __align__(16) float xstage[2][D * 6];   // raw x, one block ahead

  const int r = (wave >= 2) ? (wave - 2) * 64 + lane : 0;   // helper proj row

  float w0[32] = {}, w1[32] = {};
  float wI[6] = {};
  float bp1 = 0.f, bp2 = 0.f;

  if (wave == 0) {
#pragma unroll
    for (int k = 0; k < 32; ++k) {
      w0[k] = Whh1[lane * 32 + k];
      w1[k] = Whh1[(lane + 64) * 32 + k];
    }
  } else if (wave == 1) {
#pragma unroll
    for (int k = 0; k < 32; ++k) {
      w0[k] = Whh2[lane * 32 + k];
      w1[k] = Whh2[(lane + 64) * 32 + k];
    }
  } else {
#pragma unroll
    for (int k = 0; k < 32; ++k) w0[k] = Wih2[r * 32 + k];
#pragma unroll
    for (int k = 0; k < 6; ++k)  wI[k] = Wih1[r * 6 + k];
    bp1 = bih1[r] + bhh1[r];
    bp2 = bih2[r] + bhh2[r];
  }

  // Per-lane activation constants (branch-free activations):
  // lane<32 handles rows (i_u, g_u): a1 = tanh = 2*sigma(2x)-1
  // lane>=32 handles rows (f_u, o_u): a1 = sigma(x)
  const float sK = lower ? (2.0f * KNEG) : KNEG;
  const float mA = lower ? 2.0f : 1.0f;
  const float aA = lower ? -1.0f : 0.0f;

  float hval = 0.f, cval = 0.f;

  // ---- prologue: helpers compute pin1 for block 0 (direct global reads)
  //      and stage x of block 1 into xstage[1].
  if (wave >= 2) {
#pragma unroll
    for (int j = 0; j < D; ++j) {
      const float* xp = x + ((size_t)j * NCH + n) * 6;
      const float2 xa = *(const float2*)(xp + 0);
      const float2 xm = *(const float2*)(xp + 2);
      const float2 xc = *(const float2*)(xp + 4);
      float acc = bp1;
      acc = fmaf(xa.x, wI[0], acc); acc = fmaf(xa.y, wI[1], acc);
      acc = fmaf(xm.x, wI[2], acc); acc = fmaf(xm.y, wI[3], acc);
      acc = fmaf(xc.x, wI[4], acc); acc = fmaf(xc.y, wI[5], acc);
      pin1[0][j][r] = acc;
    }
    if (r < D * 6) {
      xstage[1][r] = x[(((size_t)D + r / 6) * NCH + n) * 6 + (r % 6)];
    }
  }

  for (int b = 0; b < NB + 2; ++b) {
    BAR();   // one barrier per D steps; vmcnt never drained in-loop
    const int p = b & 1;

    if (wave == 0) {
      // ---- layer-1: D steps fully in-wave ----
      if (b < NB) {
        float pcA = pin1[p][0][lane];
        float pcB = pin1[p][0][lane + 64];
#pragma unroll
        for (int j = 0; j < D; ++j) {
          float pnA = 0.f, pnB = 0.f;
          if (j + 1 < D) { pnA = pin1[p][j + 1][lane]; pnB = pin1[p][j + 1][lane + 64]; }
          float c0a = 0.f, c0b = 0.f, c0c = 0.f, c0d = 0.f;
          float c1a = 0.f, c1b = 0.f, c1c = 0.f, c1d = 0.f;
#pragma unroll
          for (int k = 0; k < 8; ++k) {
            const float h0 = rl(hval, k),      h1 = rl(hval, k + 8);
            const float h2 = rl(hval, k + 16), h3 = rl(hval, k + 24);
            c0a = fmaf(h0, w0[k],      c0a);  c1a = fmaf(h0, w1[k],      c1a);
            c0b = fmaf(h1, w0[k + 8],  c0b);  c1b = fmaf(h1, w1[k + 8],  c1b);
            c0c = fmaf(h2, w0[k + 16], c0c);  c1c = fmaf(h2, w1[k + 16], c1c);
            c0d = fmaf(h3, w0[k + 24], c0d);  c1d = fmaf(h3, w1[k + 24], c1d);
          }
          const float acc0 = ((c0a + c0b) + (c0c + c0d)) + pcA;
          const float acc1 = ((c1a + c1b) + (c1c + c1d)) + pcB;
          // uniform activations: a0 = sigma(acc0) (i|f); a1 = tanh|sigma (g|o)
          const float a0 = vrcp(1.0f + vexp2(acc0 * KNEG));
          const float q  = vrcp(1.0f + vexp2(acc1 * sK));
          const float a1 = fmaf(mA, q, aA);
          // exchange: lower gets (f,o) from upper; upper's c/h are garbage
          // (never read: readlane uses k<32, stores are lower-masked).
          const float fv = __shfl_xor(a0, 32, 64);
          const float ov = __shfl_xor(a1, 32, 64);
          const float ig = a0 * a1;
          cval = fmaf(fv, cval, ig);
          hval = ov * tanhv(cval);
          if (lower) h1s[p][j][u] = hval;
          pcA = pnA; pcB = pnB;
        }
      }
    } else if (wave == 1) {
      // ---- layer-2: D steps of block b-2 ----
      if (b >= 2) {
        const int t0 = (b - 2) * D;
        float pcA = pin2[p][0][lane];
        float pcB = pin2[p][0][lane + 64];
#pragma unroll
        for (int j = 0; j < D; ++j) {
          float pnA = 0.f, pnB = 0.f;
          if (j + 1 < D) { pnA = pin2[p][j + 1][lane]; pnB = pin2[p][j + 1][lane + 64]; }
          float c0a = 0.f, c0b = 0.f, c0c = 0.f, c0d = 0.f;
          float c1a = 0.f, c1b = 0.f, c1c = 0.f, c1d = 0.f;
#pragma unroll
          for (int k = 0; k < 8; ++k) {
            const float h0 = rl(hval, k),      h1 = rl(hval, k + 8);
            const float h2 = rl(hval, k + 16), h3 = rl(hval, k + 24);
            c0a = fmaf(h0, w0[k],      c0a);  c1a = fmaf(h0, w1[k],      c1a);
            c0b = fmaf(h1, w0[k + 8],  c0b);  c1b = fmaf(h1, w1[k + 8],  c1b);
            c0c = fmaf(h2, w0[k + 16], c0c);  c1c = fmaf(h2, w1[k + 16], c1c);
            c0d = fmaf(h3, w0[k + 24], c0d);  c1d = fmaf(h3, w1[k + 24], c1d);
          }
          const float acc0 = ((c0a + c0b) + (c0c + c0d)) + pcA;
          const float acc1 = ((c1a + c1b) + (c1c + c1d)) + pcB;
          const float a0 = vrcp(1.0f + vexp2(acc0 * KNEG));
          const float q  = vrcp(1.0f + vexp2(acc1 * sK));
          const float a1 = fmaf(mA, q, aA);
          const float fv = __shfl_xor(a0, 32, 64);
          const float ov = __shfl_xor(a1, 32, 64);
          const float ig = a0 * a1;
          cval = fmaf(fv, cval, ig);
          hval = ov * tanhv(cval);
          if (lower) ys2[((size_t)(t0 + j) * NCH + n) * 32 + u] = hval;
          pcA = pnA; pcB = pnB;
        }
      }
    } else {
      // ---- helpers ----
      // (1) issue global x loads for block b+2 (consumed at (4), latency
      //     hidden under (2)+(3); BAR never waits vmcnt).
      float xr = 0.f;
      const bool doLoad = (r < D * 6) && (b + 2 < NB);
      if (doLoad)
        xr = x[(((size_t)(b + 2) * D + r / 6) * NCH + n) * 6 + (r % 6)];
      // (2) pin2 for block b-1 from h1s (float4 broadcast, 1-ahead prefetch)
      if (b >= 1 && b <= NB) {
        const int q2 = (b - 1) & 1;
        float4 hp[8];
#pragma unroll
        for (int qq = 0; qq < 8; ++qq) hp[qq] = ((const float4*)&h1s[q2][0][0])[qq];
#pragma unroll
        for (int j = 0; j < D; ++j) {
          float4 hn[8];
          if (j + 1 < D) {
#pragma unroll
            for (int qq = 0; qq < 8; ++qq)
              hn[qq] = ((const float4*)&h1s[q2][j + 1][0])[qq];
          }
          float a0 = 0.f, a1 = 0.f, a2 = 0.f, a3 = 0.f;
#pragma unroll
          for (int qq = 0; qq < 8; ++qq) {
            const float4 hv4 = hp[qq];
            a0 = fmaf(hv4.x, w0[4 * qq + 0], a0);
            a1 = fmaf(hv4.y, w0[4 * qq + 1], a1);
            a2 = fmaf(hv4.z, w0[4 * qq + 2], a2);
            a3 = fmaf(hv4.w, w0[4 * qq + 3], a3);
          }
          pin2[q2][j][r] = bp2 + ((a0 + a1) + (a2 + a3));
          if (j + 1 < D) {
#pragma unroll
            for (int qq = 0; qq < 8; ++qq) hp[qq] = hn[qq];
          }
        }
      }
      // (3) pin1 for block b+1 from xstage (LDS broadcast reads)
      if (b + 1 < NB) {
        const int s2 = (b + 1) & 1;
#pragma unroll
        for (int j = 0; j < D; ++j) {
          const float* xs = &xstage[s2][j * 6];
          const float2 xa = *(const float2*)(xs + 0);
          const float2 xm = *(const float2*)(xs + 2);
          const float2 xc = *(const float2*)(xs + 4);
          float acc = bp1;
          acc = fmaf(xa.x, wI[0], acc); acc = fmaf(xa.y, wI[1], acc);
          acc = fmaf(xm.x, wI[2], acc); acc = fmaf(xm.y, wI[3], acc);
          acc = fmaf(xc.x, wI[4], acc); acc = fmaf(xc.y, wI[5], acc);
          pin1[s2][j][r] = acc;
        }
      }
      // (4) write staged x for block b+2 (waits vmcnt for xr only)
      if (doLoad) xstage[b & 1][r] = xr;
    }
  }
}

// MLP head: z(16384,640) -> relu(640->128) -> relu(128->32) -> 2.
__global__ __launch_bounds__(128, 1)
void head_kernel(const float* __restrict__ ys2,
                 const float* __restrict__ W1, const float* __restrict__ b1,
                 const float* __restrict__ W2, const float* __restrict__ b2,
                 const float* __restrict__ W3, const float* __restrict__ b3,
                 float* __restrict__ out)
{
  const int R = 16;
  const int b0 = blockIdx.x * R;
  const int tid = threadIdx.x;

  __shared__ __align__(16) float zl[R][640];
  __shared__ float z1[R][128];
  __shared__ float z2[R][32];

  {
    const float4* src = (const float4*)(ys2 + (size_t)b0 * 640);
    float4* dst = (float4*)&zl[0][0];
    for (int i = tid; i < R * 160; i += 128) dst[i] = src[i];
  }
  __syncthreads();

  {
    float acc[R];
    const float bb = b1[tid];
#pragma unroll
    for (int r = 0; r < R; ++r) acc[r] = bb;
    for (int kk = 0; kk < 640; kk += 4) {
      const float4 w = *(const float4*)&W1[(size_t)tid * 640 + kk];
#pragma unroll
      for (int r = 0; r < R; ++r) {
        const float4 z4 = *(const float4*)&zl[r][kk];
        acc[r] = fmaf(w.x, z4.x, fmaf(w.y, z4.y, fmaf(w.z, z4.z, fmaf(w.w, z4.w, acc[r]))));
      }
    }
#pragma unroll
    for (int r = 0; r < R; ++r) z1[r][tid] = fmaxf(acc[r], 0.f);
  }
  __syncthreads();

  {
    const int jo = tid & 31, rg = tid >> 5;
    float a2[4];
    const float bb = b2[jo];
#pragma unroll
    for (int q = 0; q < 4; ++q) a2[q] = bb;
    for (int k = 0; k < 128; ++k) {
      const float w = W2[jo * 128 + k];
#pragma unroll
      for (int q = 0; q < 4; ++q) a2[q] = fmaf(w, z1[rg + 4 * q][k], a2[q]);
    }
#pragma unroll
    for (int q = 0; q < 4; ++q) z2[rg + 4 * q][jo] = fmaxf(a2[q], 0.f);
  }
  __syncthreads();

  if (tid < 32) {
    const int r = tid >> 1, jo = tid & 1;
    float a = b3[jo];
#pragma unroll
    for (int k = 0; k < 32; ++k) a = fmaf(W3[jo * 32 + k], z2[r][k], a);
    out[(size_t)(b0 + r) * 2 + jo] = a;
  }
}

extern "C" void kernel_launch(void* const* d_in, const int* in_sizes, int n_in,
                              void* d_out, int out_size, void* d_ws, size_t ws_size,
                              hipStream_t stream) {
  (void)in_sizes; (void)n_in; (void)out_size; (void)ws_size;
  const float* x    = (const float*)d_in[0];
  const float* Wih1 = (const float*)d_in[1];
  const float* Whh1 = (const float*)d_in[2];
  const float* bih1 = (const float*)d_in[3];
  const float* bhh1 = (const float*)d_in[4];
  const float* Wih2 = (const float*)d_in[5];
  const float* Whh2 = (const float*)d_in[6];
  const float* bih2 = (const float*)d_in[7];
  const float* bhh2 = (const float*)d_in[8];
  const float* W1   = (const float*)d_in[9];
  const float* b1   = (const float*)d_in[10];
  const float* W2   = (const float*)d_in[11];
  const float* b2   = (const float*)d_in[12];
  const float* W3   = (const float*)d_in[13];
  const float* b3   = (const float*)d_in[14];
  float* out = (float*)d_out;

  float* ys2 = (float*)d_ws;   // (16384, 20, 32) fp32 = 41.9 MB

  lstm2_kernel<<<NCH, 256, 0, stream>>>(x, Wih1, Whh1, bih1, bhh1,
                                        Wih2, Whh2, bih2, bhh2, ys2);
  head_kernel<<<NSTEP / 16, 128, 0, stream>>>(ys2, W1, b1, W2, b2, W3, b3, out);
}

// Round 8
// 4528.944 us; speedup vs baseline: 2.0333x; 1.0612x over previous
//
#include <hip/hip_runtime.h>

// Problem constants (fixed by the reference).
#define NSTEP 16384   // scan length (== B)
#define NCH   20      // independent chains (== T)
#define D     16      // steps per barrier block
#define NB    (NSTEP / D)   // 1024 blocks
// hidden = 32, gates = 128 per layer (torch order i,f,g,o).

// Raw barrier: order LDS (lgkmcnt) but leave global loads/stores in flight.
#define BAR() asm volatile("s_waitcnt lgkmcnt(0)\n\ts_barrier" ::: "memory")

__device__ __forceinline__ float rl(float v, int l) {
  return __builtin_bit_cast(float, __builtin_amdgcn_readlane(__builtin_bit_cast(int, v), l));
}
// Raw transcendentals: v_exp_f32 (2^x) and v_rcp_f32 (~1ulp each).
__device__ __forceinline__ float vexp2(float x) {
  float r; asm("v_exp_f32 %0, %1" : "=v"(r) : "v"(x)); return r;
}
__device__ __forceinline__ float vrcp(float x) {
  float r; asm("v_rcp_f32 %0, %1" : "=v"(r) : "v"(x)); return r;
}
#define KNEG (-1.4426950408889634f)   // -log2(e)

__device__ __forceinline__ float tanhv(float x) {
  // tanh(x) = 2*sigma(2x)-1 ; inf-safe (exp2->inf => rcp->0 => -1).
  const float e = vexp2(x * (2.0f * KNEG));
  return fmaf(2.0f, vrcp(1.0f + e), -1.0f);
}

// lane l <-> lane l^32 value exchange on the VALU pipe (v_permlane32_swap),
// replacing __shfl_xor(x,32,64) which lowers via the LDS pipe (ds_swizzle,
// ~40cy + lgkmcnt) and sat on the recurrent c-update chain.
// Builtin returns a uint32x2 vector: elem0 = old vdst lane pairing, elem1 =
// the swapped value for this lane's counterpart; selecting by half gives
// the counterpart's value in both halves.
__device__ __forceinline__ float xswap(float a, bool lower) {
  auto r = __builtin_amdgcn_permlane32_swap(__builtin_bit_cast(int, a),
                                            __builtin_bit_cast(int, a),
                                            false, false);
  // r[0]: lane<32 -> a[lane],    lane>=32 -> a[lane-32]
  // r[1]: lane<32 -> a[lane+32], lane>=32 -> a[lane]
  return __builtin_bit_cast(float, lower ? r[1] : r[0]);
}

// Keep 8 floats register-resident at this point (no code emitted).
#define PIN8(a, o) asm volatile("" : "+v"(a[o]), "+v"(a[o+1]), "+v"(a[o+2]), \
  "+v"(a[o+3]), "+v"(a[o+4]), "+v"(a[o+5]), "+v"(a[o+6]), "+v"(a[o+7]))

// 4 waves (256 threads), one block per chain n, 1 wave/SIMD.
// Block-pipelined: ONE barrier per D=16 steps. Recurrences fully in-wave:
// readlane dot (weights pre-scaled by -log2(e); 2x for g-rows) ->
// rcp(1+exp2(acc)) activations -> permlane32_swap gate exchange.
//
// Pipeline (block index b, one barrier between consecutive b):
//   wave0 (L1): steps [bD,(b+1)D): h1 recurrence from pin1[b]; h1 -> h1s[b&1]
//   waves2,3:   pin2 for block b-1 (from h1s); pin1 for block b+1 (from
//               xstage LDS); stage x for b+2. pins are pre-scaled.
//   wave1 (L2): steps of block b-2 from pin2; stores ys2.
__global__ __attribute__((amdgpu_flat_work_group_size(256, 256),
                          amdgpu_waves_per_eu(1, 1)))
void lstm2_kernel(const float* __restrict__ x,
                  const float* __restrict__ Wih1, const float* __restrict__ Whh1,
                  const float* __restrict__ bih1, const float* __restrict__ bhh1,
                  const float* __restrict__ Wih2, const float* __restrict__ Whh2,
                  const float* __restrict__ bih2, const float* __restrict__ bhh2,
                  float* __restrict__ ys2)
{
  const int n    = blockIdx.x;
  const int tid  = threadIdx.x;
  const int wave = tid >> 6;
  const int lane = tid & 63;
  const int u    = lane & 31;
  const bool lower = (lane < 32);

  __shared__ __align__(16) float h1s [2][D][32];
  __shared__ __align__(16) float pin1[2][D][128];
  __shared__ __align__(16) float pin2[2][D][128];
  __shared__ __align__(16) float xstage[2][D * 6];   // raw x, one block ahead

  const int r = (wave >= 2) ? (wave - 2) * 64 + lane : 0;   // helper proj row
  // Row gate-scale: g-rows (64..95) get 2*KNEG (tanh via sigma(2x)); else KNEG.
  const float rsHelp = (r >= 64 && r < 96) ? (2.0f * KNEG) : KNEG;
  const float sK = lower ? (2.0f * KNEG) : KNEG;   // scale for w1 rows (g|o)

  float w0[32] = {}, w1[32] = {};
  float wI[6] = {};
  float bp1 = 0.f, bp2 = 0.f;

  if (wave == 0) {
#pragma unroll
    for (int k = 0; k < 32; ++k) {
      w0[k] = Whh1[lane * 32 + k] * KNEG;          // rows i|f
      w1[k] = Whh1[(lane + 64) * 32 + k] * sK;     // rows g|o
    }
  } else if (wave == 1) {
#pragma unroll
    for (int k = 0; k < 32; ++k) {
      w0[k] = Whh2[lane * 32 + k] * KNEG;
      w1[k] = Whh2[(lane + 64) * 32 + k] * sK;
    }
  } else {
#pragma unroll
    for (int k = 0; k < 32; ++k) w0[k] = Wih2[r * 32 + k] * rsHelp;
#pragma unroll
    for (int k = 0; k < 6; ++k)  wI[k] = Wih1[r * 6 + k] * rsHelp;
    bp1 = (bih1[r] + bhh1[r]) * rsHelp;
    bp2 = (bih2[r] + bhh2[r]) * rsHelp;
  }

  // Activation affine (branch-free): lane<32 rows (i,g): a1 = 2q-1 (tanh);
  // lane>=32 rows (f,o): a1 = q (sigma). a0 is always sigma.
  const float mA = lower ? 2.0f : 1.0f;
  const float aA = lower ? -1.0f : 0.0f;

  float hval = 0.f, cval = 0.f;

  // ---- prologue: helpers compute pin1 for block 0 (direct global reads)
  //      and stage x of block 1 into xstage[1].
  if (wave >= 2) {
#pragma unroll
    for (int j = 0; j < D; ++j) {
      const float* xp = x + ((size_t)j * NCH + n) * 6;
      const float2 xa = *(const float2*)(xp + 0);
      const float2 xm = *(const float2*)(xp + 2);
      const float2 xc = *(const float2*)(xp + 4);
      float acc = bp1;
      acc = fmaf(xa.x, wI[0], acc); acc = fmaf(xa.y, wI[1], acc);
      acc = fmaf(xm.x, wI[2], acc); acc = fmaf(xm.y, wI[3], acc);
      acc = fmaf(xc.x, wI[4], acc); acc = fmaf(xc.y, wI[5], acc);
      pin1[0][j][r] = acc;
    }
    if (r < D * 6) {
      xstage[1][r] = x[(((size_t)D + r / 6) * NCH + n) * 6 + (r % 6)];
    }
  }

  for (int b = 0; b < NB + 2; ++b) {
    BAR();   // one barrier per D steps; vmcnt never drained in-loop
    const int p = b & 1;

    if (wave == 0) {
      // ---- layer-1: D steps fully in-wave ----
      if (b < NB) {
        // Pull the whole block's pins into registers up front; the step
        // loop then touches LDS only for the h1s store.
        float pa[D], pb[D];
#pragma unroll
        for (int j = 0; j < D; ++j) {
          pa[j] = pin1[p][j][lane];
          pb[j] = pin1[p][j][lane + 64];
        }
        PIN8(pa, 0); PIN8(pa, 8); PIN8(pb, 0); PIN8(pb, 8);
#pragma unroll
        for (int j = 0; j < D; ++j) {
          float c0a = pa[j], c0b = 0.f, c0c = 0.f, c0d = 0.f;
          float c1a = pb[j], c1b = 0.f, c1c = 0.f, c1d = 0.f;
#pragma unroll
          for (int k = 0; k < 8; ++k) {
            const float h0 = rl(hval, k),      h1 = rl(hval, k + 8);
            const float h2 = rl(hval, k + 16), h3 = rl(hval, k + 24);
            c0a = fmaf(h0, w0[k],      c0a);  c1a = fmaf(h0, w1[k],      c1a);
            c0b = fmaf(h1, w0[k + 8],  c0b);  c1b = fmaf(h1, w1[k + 8],  c1b);
            c0c = fmaf(h2, w0[k + 16], c0c);  c1c = fmaf(h2, w1[k + 16], c1c);
            c0d = fmaf(h3, w0[k + 24], c0d);  c1d = fmaf(h3, w1[k + 24], c1d);
          }
          const float acc0 = (c0a + c0b) + (c0c + c0d);   // pre-scaled by KNEG
          const float acc1 = (c1a + c1b) + (c1c + c1d);
          const float a0 = vrcp(1.0f + vexp2(acc0));      // sigma (i|f)
          const float q  = vrcp(1.0f + vexp2(acc1));
          const float a1 = fmaf(mA, q, aA);               // tanh(g) | sigma(o)
          const float fv = xswap(a0, lower);
          const float ov = xswap(a1, lower);
          const float ig = a0 * a1;
          // lower lanes hold the true c,h; upper lanes are garbage (never read)
          cval = fmaf(fv, cval, ig);
          hval = ov * tanhv(cval);
          if (lower) h1s[p][j][u] = hval;
        }
      }
    } else if (wave == 1) {
      // ---- layer-2: D steps of block b-2 ----
      if (b >= 2) {
        const int t0 = (b - 2) * D;
        float pa[D], pb[D];
#pragma unroll
        for (int j = 0; j < D; ++j) {
          pa[j] = pin2[p][j][lane];
          pb[j] = pin2[p][j][lane + 64];
        }
        PIN8(pa, 0); PIN8(pa, 8); PIN8(pb, 0); PIN8(pb, 8);
#pragma unroll
        for (int j = 0; j < D; ++j) {
          float c0a = pa[j], c0b = 0.f, c0c = 0.f, c0d = 0.f;
          float c1a = pb[j], c1b = 0.f, c1c = 0.f, c1d = 0.f;
#pragma unroll
          for (int k = 0; k < 8; ++k) {
            const float h0 = rl(hval, k),      h1 = rl(hval, k + 8);
            const float h2 = rl(hval, k + 16), h3 = rl(hval, k + 24);
            c0a = fmaf(h0, w0[k],      c0a);  c1a = fmaf(h0, w1[k],      c1a);
            c0b = fmaf(h1, w0[k + 8],  c0b);  c1b = fmaf(h1, w1[k + 8],  c1b);
            c0c = fmaf(h2, w0[k + 16], c0c);  c1c = fmaf(h2, w1[k + 16], c1c);
            c0d = fmaf(h3, w0[k + 24], c0d);  c1d = fmaf(h3, w1[k + 24], c1d);
          }
          const float acc0 = (c0a + c0b) + (c0c + c0d);
          const float acc1 = (c1a + c1b) + (c1c + c1d);
          const float a0 = vrcp(1.0f + vexp2(acc0));
          const float q  = vrcp(1.0f + vexp2(acc1));
          const float a1 = fmaf(mA, q, aA);
          const float fv = xswap(a0, lower);
          const float ov = xswap(a1, lower);
          const float ig = a0 * a1;
          cval = fmaf(fv, cval, ig);
          hval = ov * tanhv(cval);
          if (lower) ys2[((size_t)(t0 + j) * NCH + n) * 32 + u] = hval;
        }
      }
    } else {
      // ---- helpers ----
      // (1) issue global x loads for block b+2 (consumed at (4); BAR never
      //     waits vmcnt, latency hidden under (2)+(3)).
      float xr = 0.f;
      const bool doLoad = (r < D * 6) && (b + 2 < NB);
      if (doLoad)
        xr = x[(((size_t)(b + 2) * D + r / 6) * NCH + n) * 6 + (r % 6)];
      // (2) pin2 for block b-1 from h1s (float4 broadcast, 1-ahead prefetch)
      if (b >= 1 && b <= NB) {
        const int q2 = (b - 1) & 1;
        float4 hp[8];
#pragma unroll
        for (int qq = 0; qq < 8; ++qq) hp[qq] = ((const float4*)&h1s[q2][0][0])[qq];
#pragma unroll
        for (int j = 0; j < D; ++j) {
          float4 hn[8];
          if (j + 1 < D) {
#pragma unroll
            for (int qq = 0; qq < 8; ++qq)
              hn[qq] = ((const float4*)&h1s[q2][j + 1][0])[qq];
          }
          float a0 = 0.f, a1 = 0.f, a2 = 0.f, a3 = 0.f;
#pragma unroll
          for (int qq = 0; qq < 8; ++qq) {
            const float4 hv4 = hp[qq];
            a0 = fmaf(hv4.x, w0[4 * qq + 0], a0);
            a1 = fmaf(hv4.y, w0[4 * qq + 1], a1);
            a2 = fmaf(hv4.z, w0[4 * qq + 2], a2);
            a3 = fmaf(hv4.w, w0[4 * qq + 3], a3);
          }
          pin2[q2][j][r] = bp2 + ((a0 + a1) + (a2 + a3));
          if (j + 1 < D) {
#pragma unroll
            for (int qq = 0; qq < 8; ++qq) hp[qq] = hn[qq];
          }
        }
      }
      // (3) pin1 for block b+1 from xstage (LDS broadcast reads)
      if (b + 1 < NB) {
        const int s2 = (b + 1) & 1;
#pragma unroll
        for (int j = 0; j < D; ++j) {
          const float* xs = &xstage[s2][j * 6];
          const float2 xa = *(const float2*)(xs + 0);
          const float2 xm = *(const float2*)(xs + 2);
          const float2 xc = *(const float2*)(xs + 4);
          float acc = bp1;
          acc = fmaf(xa.x, wI[0], acc); acc = fmaf(xa.y, wI[1], acc);
          acc = fmaf(xm.x, wI[2], acc); acc = fmaf(xm.y, wI[3], acc);
          acc = fmaf(xc.x, wI[4], acc); acc = fmaf(xc.y, wI[5], acc);
          pin1[s2][j][r] = acc;
        }
      }
      // (4) write staged x for block b+2 (waits vmcnt for xr only)
      if (doLoad) xstage[b & 1][r] = xr;
    }
  }
}

// MLP head: z(16384,640) -> relu(640->128) -> relu(128->32) -> 2.
__global__ __launch_bounds__(128, 1)
void head_kernel(const float* __restrict__ ys2,
                 const float* __restrict__ W1, const float* __restrict__ b1,
                 const float* __restrict__ W2, const float* __restrict__ b2,
                 const float* __restrict__ W3, const float* __restrict__ b3,
                 float* __restrict__ out)
{
  const int R = 16;
  const int b0 = blockIdx.x * R;
  const int tid = threadIdx.x;

  __shared__ __align__(16) float zl[R][640];
  __shared__ float z1[R][128];
  __shared__ float z2[R][32];

  {
    const float4* src = (const float4*)(ys2 + (size_t)b0 * 640);
    float4* dst = (float4*)&zl[0][0];
    for (int i = tid; i < R * 160; i += 128) dst[i] = src[i];
  }
  __syncthreads();

  {
    float acc[R];
    const float bb = b1[tid];
#pragma unroll
    for (int r = 0; r < R; ++r) acc[r] = bb;
    for (int kk = 0; kk < 640; kk += 4) {
      const float4 w = *(const float4*)&W1[(size_t)tid * 640 + kk];
#pragma unroll
      for (int r = 0; r < R; ++r) {
        const float4 z4 = *(const float4*)&zl[r][kk];
        acc[r] = fmaf(w.x, z4.x, fmaf(w.y, z4.y, fmaf(w.z, z4.z, fmaf(w.w, z4.w, acc[r]))));
      }
    }
#pragma unroll
    for (int r = 0; r < R; ++r) z1[r][tid] = fmaxf(acc[r], 0.f);
  }
  __syncthreads();

  {
    const int jo = tid & 31, rg = tid >> 5;
    float a2[4];
    const float bb = b2[jo];
#pragma unroll
    for (int q = 0; q < 4; ++q) a2[q] = bb;
    for (int k = 0; k < 128; ++k) {
      const float w = W2[jo * 128 + k];
#pragma unroll
      for (int q = 0; q < 4; ++q) a2[q] = fmaf(w, z1[rg + 4 * q][k], a2[q]);
    }
#pragma unroll
    for (int q = 0; q < 4; ++q) z2[rg + 4 * q][jo] = fmaxf(a2[q], 0.f);
  }
  __syncthreads();

  if (tid < 32) {
    const int r = tid >> 1, jo = tid & 1;
    float a = b3[jo];
#pragma unroll
    for (int k = 0; k < 32; ++k) a = fmaf(W3[jo * 32 + k], z2[r][k], a);
    out[(size_t)(b0 + r) * 2 + jo] = a;
  }
}

extern "C" void kernel_launch(void* const* d_in, const int* in_sizes, int n_in,
                              void* d_out, int out_size, void* d_ws, size_t ws_size,
                              hipStream_t stream) {
  (void)in_sizes; (void)n_in; (void)out_size; (void)ws_size;
  const float* x    = (const float*)d_in[0];
  const float* Wih1 = (const float*)d_in[1];
  const float* Whh1 = (const float*)d_in[2];
  const float* bih1 = (const float*)d_in[3];
  const float* bhh1 = (const float*)d_in[4];
  const float* Wih2 = (const float*)d_in[5];
  const float* Whh2 = (const float*)d_in[6];
  const float* bih2 = (const float*)d_in[7];
  const float* bhh2 = (const float*)d_in[8];
  const float* W1   = (const float*)d_in[9];
  const float* b1   = (const float*)d_in[10];
  const float* W2   = (const float*)d_in[11];
  const float* b2   = (const float*)d_in[12];
  const float* W3   = (const float*)d_in[13];
  const float* b3   = (const float*)d_in[14];
  float* out = (float*)d_out;

  float* ys2 = (float*)d_ws;   // (16384, 20, 32) fp32 = 41.9 MB

  lstm2_kernel<<<NCH, 256, 0, stream>>>(x, Wih1, Whh1, bih1, bhh1,
                                        Wih2, Whh2, bih2, bhh2, ys2);
  head_kernel<<<NSTEP / 16, 128, 0, stream>>>(ys2, W1, b1, W2, b2, W3, b3, out);
}